// Round 1
// baseline (7550.979 us; speedup 1.0000x reference)
//
#include <hip/hip_runtime.h>
#include <math.h>

// ---- problem dims (fixed by setup_inputs) ----
constexpr int Bsz = 512;    // batch
constexpr int Kf  = 36;     // feature slots
constexpr int Dd  = 2048;   // feat dim
constexpr int Aa  = 512;    // att dim
constexpr int Hh  = 512;    // hidden
constexpr int Em  = 300;    // embedding dim
constexpr int Vv  = 10000;  // vocab
constexpr int TSTEPS = 19;  // MAX_LEN-1
constexpr int BOS = 1;

#define CDIV(a,b) (((a)+(b)-1)/(b))

__device__ __forceinline__ float sigm(float v) { return 1.0f / (1.0f + expf(-v)); }

// ============================================================
// Generic fp32 GEMM: C[M,N] = A[M,K] @ B[N,K]^T (+bias1+bias2+addC) or C += ...
// M must be divisible by 64 (true for all call sites: 512, 18432).
// ============================================================
constexpr int GBM = 64, GBN = 64, GBK = 16;

__global__ __launch_bounds__(256)
void gemm_nt(const float* __restrict__ A, int lda,
             const float* __restrict__ Bm, int ldb,
             float* __restrict__ C, int ldc,
             int N, int K,
             const float* __restrict__ bias1,
             const float* __restrict__ bias2,
             const float* __restrict__ addC,
             int acc)
{
    __shared__ float As[GBK][GBM];
    __shared__ float Bs[GBK][GBN];
    const int m0 = blockIdx.y * GBM;
    const int n0 = blockIdx.x * GBN;
    const int tid = threadIdx.x;
    const int tr = tid >> 4;       // 0..15
    const int tc = tid & 15;       // 0..15
    const int sm  = tid >> 2;      // 0..63 stage row
    const int sk4 = (tid & 3) * 4; // 0,4,8,12

    float accv[4][4] = {};

    const int ktiles = CDIV(K, GBK);
    for (int kt = 0; kt < ktiles; ++kt) {
        const int k0 = kt * GBK;
        // ---- stage A tile ----
        {
            const int gm = m0 + sm;
            const int gk = k0 + sk4;
            float4 v;
            if (gk + 3 < K) {
                v = *reinterpret_cast<const float4*>(&A[(size_t)gm * lda + gk]);
            } else {
                v.x = (gk + 0 < K) ? A[(size_t)gm * lda + gk + 0] : 0.f;
                v.y = (gk + 1 < K) ? A[(size_t)gm * lda + gk + 1] : 0.f;
                v.z = (gk + 2 < K) ? A[(size_t)gm * lda + gk + 2] : 0.f;
                v.w = (gk + 3 < K) ? A[(size_t)gm * lda + gk + 3] : 0.f;
            }
            As[sk4 + 0][sm] = v.x; As[sk4 + 1][sm] = v.y;
            As[sk4 + 2][sm] = v.z; As[sk4 + 3][sm] = v.w;
        }
        // ---- stage B tile ----
        {
            const int gn = n0 + sm;
            const int gk = k0 + sk4;
            float4 v = {0.f, 0.f, 0.f, 0.f};
            if (gn < N) {
                if (gk + 3 < K) {
                    v = *reinterpret_cast<const float4*>(&Bm[(size_t)gn * ldb + gk]);
                } else {
                    v.x = (gk + 0 < K) ? Bm[(size_t)gn * ldb + gk + 0] : 0.f;
                    v.y = (gk + 1 < K) ? Bm[(size_t)gn * ldb + gk + 1] : 0.f;
                    v.z = (gk + 2 < K) ? Bm[(size_t)gn * ldb + gk + 2] : 0.f;
                    v.w = (gk + 3 < K) ? Bm[(size_t)gn * ldb + gk + 3] : 0.f;
                }
            }
            Bs[sk4 + 0][sm] = v.x; Bs[sk4 + 1][sm] = v.y;
            Bs[sk4 + 2][sm] = v.z; Bs[sk4 + 3][sm] = v.w;
        }
        __syncthreads();
        #pragma unroll
        for (int k = 0; k < GBK; ++k) {
            float a[4], b[4];
            #pragma unroll
            for (int i = 0; i < 4; ++i) a[i] = As[k][tr * 4 + i];
            #pragma unroll
            for (int j = 0; j < 4; ++j) b[j] = Bs[k][tc * 4 + j];
            #pragma unroll
            for (int i = 0; i < 4; ++i)
                #pragma unroll
                for (int j = 0; j < 4; ++j)
                    accv[i][j] = fmaf(a[i], b[j], accv[i][j]);
        }
        __syncthreads();
    }
    // ---- write C ----
    #pragma unroll
    for (int i = 0; i < 4; ++i) {
        const int m = m0 + tr * 4 + i;
        #pragma unroll
        for (int j = 0; j < 4; ++j) {
            const int n = n0 + tc * 4 + j;
            if (n < N) {
                const size_t idx = (size_t)m * ldc + n;
                float r = accv[i][j];
                if (acc) {
                    C[idx] += r;
                } else {
                    if (bias1) r += bias1[n];
                    if (bias2) r += bias2[n];
                    if (addC)  r += addC[idx];
                    C[idx] = r;
                }
            }
        }
    }
}

// ============================================================
// init: zero h1,c1,h2,c2 (contiguous 4*B*H) and x = E[BOS]
// ============================================================
__global__ __launch_bounds__(256)
void init_kernel(float* __restrict__ state, const float* __restrict__ E,
                 float* __restrict__ x)
{
    const int idx = blockIdx.x * 256 + threadIdx.x;
    if (idx < 4 * Bsz * Hh) state[idx] = 0.f;
    if (idx < Bsz * Em) x[idx] = E[(size_t)BOS * Em + (idx % Em)];
}

// f_mean[b,a] = mean_k f_att[b,k,a]
__global__ __launch_bounds__(256)
void fmean_kernel(const float* __restrict__ f_att, float* __restrict__ f_mean)
{
    const int b = blockIdx.x;
    for (int a = threadIdx.x; a < Aa; a += 256) {
        float s = 0.f;
        for (int k = 0; k < Kf; ++k) s += f_att[((size_t)b * Kf + k) * Aa + a];
        f_mean[(size_t)b * Aa + a] = s * (1.0f / 36.0f);
    }
}

// LSTM cell elementwise: gates in g[B,4H] as [i|f|g|o]; updates h,c in place
__global__ __launch_bounds__(256)
void lstm_cell_kernel(const float* __restrict__ g, float* __restrict__ h,
                      float* __restrict__ c)
{
    const int idx = blockIdx.x * 256 + threadIdx.x;   // < B*H
    const int b = idx >> 9, hh = idx & 511;
    const float* gb = g + (size_t)b * (4 * Hh);
    const float gi = gb[hh];
    const float gf = gb[Hh + hh];
    const float gc = gb[2 * Hh + hh];
    const float go = gb[3 * Hh + hh];
    const float cv = sigm(gf) * c[idx] + sigm(gi) * tanhf(gc);
    c[idx] = cv;
    h[idx] = sigm(go) * tanhf(cv);
}

// e[b,k] = sum_a wa2[a]*tanh(att_f[b,k,a] + q[b,a]) + ba2   (one wave per (b,k))
__global__ __launch_bounds__(256)
void attn_e_kernel(const float* __restrict__ att_f, const float* __restrict__ q,
                   const float* __restrict__ wa2, const float* __restrict__ ba2,
                   float* __restrict__ e)
{
    const int wid = blockIdx.x * 4 + (threadIdx.x >> 6);
    const int lane = threadIdx.x & 63;
    const int b = wid / Kf, k = wid % Kf;
    const float* pf = att_f + ((size_t)b * Kf + k) * Aa;
    const float* pq = q + (size_t)b * Aa;
    float s = 0.f;
    for (int j = 0; j < Aa; j += 64) {
        const int a = j + lane;
        s += tanhf(pf[a] + pq[a]) * wa2[a];
    }
    #pragma unroll
    for (int off = 32; off; off >>= 1) s += __shfl_down(s, off);
    if (lane == 0) e[wid] = s + ba2[0];
}

// softmax over k (per b) then ctx[b,a] = sum_k alpha[k]*f_att[b,k,a]
__global__ __launch_bounds__(256)
void softmax_ctx_kernel(const float* __restrict__ e, const float* __restrict__ f_att,
                        float* __restrict__ ctx)
{
    const int b = blockIdx.x;
    const int tid = threadIdx.x;
    __shared__ float se[Kf];
    __shared__ float w[Kf];
    if (tid < Kf) se[tid] = e[(size_t)b * Kf + tid];
    __syncthreads();
    if (tid < Kf) {
        float mx = -INFINITY;
        for (int k = 0; k < Kf; ++k) mx = fmaxf(mx, se[k]);
        float s = 0.f;
        for (int k = 0; k < Kf; ++k) s += expf(se[k] - mx);
        w[tid] = expf(se[tid] - mx) / s;
    }
    __syncthreads();
    for (int a = tid; a < Aa; a += 256) {
        float acc = 0.f;
        for (int k = 0; k < Kf; ++k)
            acc = fmaf(w[k], f_att[((size_t)b * Kf + k) * Aa + a], acc);
        ctx[(size_t)b * Aa + a] = acc;
    }
}

// argmax over vocab (first-index tie-break, matching jnp.argmax) + embed gather
__global__ __launch_bounds__(256)
void argmax_embed_kernel(const float* __restrict__ logits, const float* __restrict__ E,
                         float* __restrict__ x, int* __restrict__ out, int t)
{
    const int b = blockIdx.x;
    const int tid = threadIdx.x;
    float best = -INFINITY;
    int bi = Vv;
    for (int j = tid; j < Vv; j += 256) {
        const float v = logits[(size_t)b * Vv + j];
        if (v > best) { best = v; bi = j; }   // strict > keeps first max in stream
    }
    __shared__ float sv[256];
    __shared__ int   si[256];
    sv[tid] = best; si[tid] = bi;
    __syncthreads();
    for (int s = 128; s > 0; s >>= 1) {
        if (tid < s) {
            const float v2 = sv[tid + s];
            const int   i2 = si[tid + s];
            if (v2 > sv[tid] || (v2 == sv[tid] && i2 < si[tid])) {
                sv[tid] = v2; si[tid] = i2;
            }
        }
        __syncthreads();
    }
    const int idx = si[0];
    if (tid == 0) out[(size_t)b * TSTEPS + t] = idx;
    for (int d = tid; d < Em; d += 256)
        x[(size_t)b * Em + d] = E[(size_t)idx * Em + d];
}

// ============================================================
// host side
// ============================================================
static inline void gemm(hipStream_t s, const float* A, int lda, const float* B, int ldb,
                        float* C, int ldc, int M, int N, int K,
                        const float* b1, const float* b2, const float* addC, int acc)
{
    dim3 grid(CDIV(N, GBN), M / GBM), blk(256);
    gemm_nt<<<grid, blk, 0, s>>>(A, lda, B, ldb, C, ldc, N, K, b1, b2, addC, acc);
}

extern "C" void kernel_launch(void* const* d_in, const int* in_sizes, int n_in,
                              void* d_out, int out_size, void* d_ws, size_t ws_size,
                              hipStream_t stream)
{
    const float* feats = (const float*)d_in[0];
    const float* Wp    = (const float*)d_in[1];
    const float* bp    = (const float*)d_in[2];
    const float* E     = (const float*)d_in[3];
    const float* Wih1  = (const float*)d_in[4];
    const float* Whh1  = (const float*)d_in[5];
    const float* bih1  = (const float*)d_in[6];
    const float* bhh1  = (const float*)d_in[7];
    const float* Wih2  = (const float*)d_in[8];
    const float* Whh2  = (const float*)d_in[9];
    const float* bih2  = (const float*)d_in[10];
    const float* bhh2  = (const float*)d_in[11];
    const float* Wa1   = (const float*)d_in[12];
    const float* ba1   = (const float*)d_in[13];
    const float* wa2   = (const float*)d_in[14];
    const float* ba2   = (const float*)d_in[15];
    const float* Wo    = (const float*)d_in[16];
    const float* bo    = (const float*)d_in[17];
    int* out = (int*)d_out;

    float* ws = (float*)d_ws;
    size_t off = 0;
    auto alloc = [&](size_t n) { float* p = ws + off; off += n; return p; };
    float* f_att  = alloc((size_t)Bsz * Kf * Aa);   // 9.4M
    float* att_f  = alloc((size_t)Bsz * Kf * Aa);   // 9.4M
    float* f_mean = alloc((size_t)Bsz * Aa);
    float* g1c    = alloc((size_t)Bsz * 4 * Hh);
    float* state  = alloc((size_t)4 * Bsz * Hh);    // h1,c1,h2,c2 contiguous
    float* h1 = state;
    float* c1 = state + (size_t)Bsz * Hh;
    float* h2 = state + (size_t)2 * Bsz * Hh;
    float* c2 = state + (size_t)3 * Bsz * Hh;
    float* x      = alloc((size_t)Bsz * Em);
    float* g      = alloc((size_t)Bsz * 4 * Hh);
    float* q      = alloc((size_t)Bsz * Aa);
    float* evec   = alloc((size_t)Bsz * Kf);
    float* ctx    = alloc((size_t)Bsz * Aa);
    float* logits = alloc((size_t)Bsz * Vv);
    (void)ws_size; (void)in_sizes; (void)n_in; (void)out_size;

    // ---- precompute ----
    init_kernel<<<dim3(CDIV(4 * Bsz * Hh, 256)), dim3(256), 0, stream>>>(state, E, x);
    // f_att = feats @ Wp.T + bp      (18432 x 512 x K2048)
    gemm(stream, feats, Dd, Wp, Dd, f_att, Aa, Bsz * Kf, Aa, Dd, bp, nullptr, nullptr, 0);
    fmean_kernel<<<dim3(Bsz), dim3(256), 0, stream>>>(f_att, f_mean);
    // att_f = f_att @ Wa1[:,H:].T + ba1
    gemm(stream, f_att, Aa, Wa1 + Hh, Hh + Aa, att_f, Aa, Bsz * Kf, Aa, Aa, ba1, nullptr, nullptr, 0);
    // g1_const = f_mean @ Wih1[:,Em:].T + bih1 + bhh1
    gemm(stream, f_mean, Aa, Wih1 + Em, Em + Aa, g1c, 4 * Hh, Bsz, 4 * Hh, Aa, bih1, bhh1, nullptr, 0);

    // ---- decode loop ----
    for (int t = 0; t < TSTEPS; ++t) {
        // g1 = x @ Wih1[:,:Em].T + g1_const ; g1 += h1 @ Whh1.T
        gemm(stream, x, Em, Wih1, Em + Aa, g, 4 * Hh, Bsz, 4 * Hh, Em, nullptr, nullptr, g1c, 0);
        gemm(stream, h1, Hh, Whh1, Hh, g, 4 * Hh, Bsz, 4 * Hh, Hh, nullptr, nullptr, nullptr, 1);
        lstm_cell_kernel<<<dim3(Bsz * Hh / 256), dim3(256), 0, stream>>>(g, h1, c1);
        // q = h1 @ Wa1[:,:H].T
        gemm(stream, h1, Hh, Wa1, Hh + Aa, q, Aa, Bsz, Aa, Hh, nullptr, nullptr, nullptr, 0);
        attn_e_kernel<<<dim3(Bsz * Kf / 4), dim3(256), 0, stream>>>(att_f, q, wa2, ba2, evec);
        softmax_ctx_kernel<<<dim3(Bsz), dim3(256), 0, stream>>>(evec, f_att, ctx);
        // g2 = h1 @ Wih2[:,:H].T + bih2+bhh2 ; += ctx @ Wih2[:,H:].T ; += h2 @ Whh2.T
        gemm(stream, h1, Hh, Wih2, Hh + Aa, g, 4 * Hh, Bsz, 4 * Hh, Hh, bih2, bhh2, nullptr, 0);
        gemm(stream, ctx, Aa, Wih2 + Hh, Hh + Aa, g, 4 * Hh, Bsz, 4 * Hh, Aa, nullptr, nullptr, nullptr, 1);
        gemm(stream, h2, Hh, Whh2, Hh, g, 4 * Hh, Bsz, 4 * Hh, Hh, nullptr, nullptr, nullptr, 1);
        lstm_cell_kernel<<<dim3(Bsz * Hh / 256), dim3(256), 0, stream>>>(g, h2, c2);
        // logits = h2 @ Wo.T + bo
        gemm(stream, h2, Hh, Wo, Hh, logits, Vv, Bsz, Vv, Hh, bo, nullptr, nullptr, 0);
        argmax_embed_kernel<<<dim3(Bsz), dim3(256), 0, stream>>>(logits, E, x, out, t);
    }
}

// Round 3
// 4797.483 us; speedup vs baseline: 1.5739x; 1.5739x over previous
//
#include <hip/hip_runtime.h>
#include <math.h>
#include <stdint.h>

// ---- problem dims ----
constexpr int Bsz = 512, Kf = 36, Dd = 2048, Aa = 512, Hh = 512, Em = 300;
constexpr int Vv = 10000, TSTEPS = 19, BOS = 1;
constexpr int K1 = 832;          // padded Em+Hh (812 -> 832, mult of 32)
constexpr int K2 = 1536;         // h1|ctx|h2
constexpr int VvP = 10112;       // vocab rows padded to mult of 128
constexpr float SPLIT_S  = 2048.0f;
constexpr float SPLIT_IS = 1.0f / 2048.0f;

#define CDIV(a,b) (((a)+(b)-1)/(b))

typedef _Float16 f16x8 __attribute__((ext_vector_type(8)));
typedef float    f32x4 __attribute__((ext_vector_type(4)));

typedef const unsigned int GU __attribute__((address_space(1)));
typedef unsigned int       LU __attribute__((address_space(3)));

__device__ __forceinline__ void gload16(const void* g, void* l) {
    __builtin_amdgcn_global_load_lds((GU*)g, (LU*)l, 16, 0, 0);
}

__device__ __forceinline__ float sigm(float v) { return 1.0f / (1.0f + expf(-v)); }

__device__ __forceinline__ void wsplit(_Float16* __restrict__ hi, _Float16* __restrict__ lo,
                                       size_t idx, float v) {
    _Float16 h = (_Float16)v;
    hi[idx] = h;
    lo[idx] = (_Float16)((v - (float)h) * SPLIT_S);
}

// ============================================================
// Split-fp16 MFMA GEMM:  C[M,N] = A[M,K] @ B[N,K]^T (+bias1+bias2+addC)
// A: either fp32 (AF32=true, in-kernel split) or pre-split fp16 hi/lo.
// B: pre-split fp16 hi/lo, row-major [N][ldb].
// K mult of 32; M mult of BM; N arbitrary (B buffer rows padded to mult BN).
// ============================================================
template<int BM, int BN, bool AF32>
__global__ __launch_bounds__(256)
void gemm_sp(const float* __restrict__ Af,
             const _Float16* __restrict__ Ahi, const _Float16* __restrict__ Alo, int lda,
             const _Float16* __restrict__ Bhi, const _Float16* __restrict__ Blo, int ldb,
             float* __restrict__ C, int ldc, int N, int K,
             const float* __restrict__ bias1, const float* __restrict__ bias2,
             const float* __restrict__ addC)
{
    constexpr int WM = BM / 2, WN = BN / 2;      // wave tile (2x2 waves)
    constexpr int MF = WM / 16, NF = WN / 16;    // 16x16 frags per wave
    constexpr int PSA = BM * 8 + 8;              // plane stride (halfs), +16B pad
    constexpr int PSB = BN * 8 + 8;
    constexpr int OFF_AH = 0, OFF_AL = 4 * PSA;
    constexpr int OFF_BH = 8 * PSA, OFF_BL = 8 * PSA + 4 * PSB;
    __shared__ _Float16 sm[8 * PSA + 8 * PSB];

    const int t    = threadIdx.x;
    const int lane = t & 63;
    const int w    = t >> 6;
    const int wr   = w >> 1, wc = w & 1;
    const int m0   = blockIdx.y * BM, n0 = blockIdx.x * BN;
    const int l15  = lane & 15, l4 = lane >> 4;

    f32x4 acch[MF][NF];
    f32x4 accm[MF][NF];
    #pragma unroll
    for (int m = 0; m < MF; ++m)
        #pragma unroll
        for (int n = 0; n < NF; ++n) {
            acch[m][n] = (f32x4){0.f, 0.f, 0.f, 0.f};
            accm[m][n] = (f32x4){0.f, 0.f, 0.f, 0.f};
        }

    const int nkt = K >> 5;
    for (int kt = 0; kt < nkt; ++kt) {
        const int k0 = kt << 5;
        __syncthreads();
        // ---- stage B (hi, lo) via global_load_lds, linear dest ----
        #pragma unroll
        for (int i = 0; i < BN / 64; ++i) {
            const int q  = i * 256 + t;
            const int c  = q / BN, r = q % BN;          // per-lane
            const int qw = i * 256 + (t & ~63);
            const int cu = qw / BN, ru = qw % BN;       // wave-uniform
            const size_t goff = (size_t)(n0 + r) * ldb + k0 + c * 8;
            gload16(Bhi + goff, &sm[OFF_BH + cu * PSB + ru * 8]);
            gload16(Blo + goff, &sm[OFF_BL + cu * PSB + ru * 8]);
        }
        // ---- stage A ----
        if constexpr (AF32) {
            #pragma unroll
            for (int i = 0; i < BM / 64; ++i) {
                const int u = i * 256 + t;              // 8-float chunk id
                const int r = u >> 2, c = u & 3;
                const float* src = Af + (size_t)(m0 + r) * lda + k0 + c * 8;
                const float4 va = *(const float4*)src;
                const float4 vb = *(const float4*)(src + 4);
                const float f[8] = {va.x, va.y, va.z, va.w, vb.x, vb.y, vb.z, vb.w};
                f16x8 hi, lo;
                #pragma unroll
                for (int j = 0; j < 8; ++j) {
                    _Float16 h = (_Float16)f[j];
                    hi[j] = h;
                    lo[j] = (_Float16)((f[j] - (float)h) * SPLIT_S);
                }
                *(f16x8*)&sm[OFF_AH + c * PSA + r * 8] = hi;
                *(f16x8*)&sm[OFF_AL + c * PSA + r * 8] = lo;
            }
        } else {
            #pragma unroll
            for (int i = 0; i < BM / 64; ++i) {
                const int q  = i * 256 + t;
                const int c  = q / BM, r = q % BM;
                const int qw = i * 256 + (t & ~63);
                const int cu = qw / BM, ru = qw % BM;
                const size_t goff = (size_t)(m0 + r) * lda + k0 + c * 8;
                gload16(Ahi + goff, &sm[OFF_AH + cu * PSA + ru * 8]);
                gload16(Alo + goff, &sm[OFF_AL + cu * PSA + ru * 8]);
            }
        }
        __syncthreads();
        // ---- frag loads + MFMA ----
        f16x8 ah[MF], al[MF], bh[NF], bl[NF];
        #pragma unroll
        for (int m = 0; m < MF; ++m) {
            const int row = wr * WM + m * 16 + l15;
            ah[m] = *(const f16x8*)&sm[OFF_AH + l4 * PSA + row * 8];
            al[m] = *(const f16x8*)&sm[OFF_AL + l4 * PSA + row * 8];
        }
        #pragma unroll
        for (int n = 0; n < NF; ++n) {
            const int row = wc * WN + n * 16 + l15;
            bh[n] = *(const f16x8*)&sm[OFF_BH + l4 * PSB + row * 8];
            bl[n] = *(const f16x8*)&sm[OFF_BL + l4 * PSB + row * 8];
        }
        #pragma unroll
        for (int m = 0; m < MF; ++m)
            #pragma unroll
            for (int n = 0; n < NF; ++n) {
                acch[m][n] = __builtin_amdgcn_mfma_f32_16x16x32_f16(ah[m], bh[n], acch[m][n], 0, 0, 0);
                accm[m][n] = __builtin_amdgcn_mfma_f32_16x16x32_f16(ah[m], bl[n], accm[m][n], 0, 0, 0);
                accm[m][n] = __builtin_amdgcn_mfma_f32_16x16x32_f16(al[m], bh[n], accm[m][n], 0, 0, 0);
            }
    }
    // ---- epilogue: C = acch + accm/S (+biases +addC) ----
    #pragma unroll
    for (int m = 0; m < MF; ++m) {
        const int rowb = m0 + wr * WM + m * 16 + l4 * 4;
        #pragma unroll
        for (int n = 0; n < NF; ++n) {
            const int col = n0 + wc * WN + n * 16 + l15;
            if (col < N) {
                float bb = 0.f;
                if (bias1) bb += bias1[col];
                if (bias2) bb += bias2[col];
                #pragma unroll
                for (int r = 0; r < 4; ++r) {
                    const size_t idx = (size_t)(rowb + r) * ldc + col;
                    float v = acch[m][n][r] + accm[m][n][r] * SPLIT_IS + bb;
                    if (addC) v += addC[idx];
                    C[idx] = v;
                }
            }
        }
    }
}

// ============================================================
// weight split-convert: dst[r][coloff+c] (hi/lo) = split(src[r][c]); r>=validR -> 0
// ============================================================
__global__ __launch_bounds__(256)
void split_convert(const float* __restrict__ src, int srcld, int validR,
                   _Float16* __restrict__ dhi, _Float16* __restrict__ dlo,
                   int dstld, int coloff, int R, int C)
{
    const int total = R * C;
    for (int i = blockIdx.x * 256 + threadIdx.x; i < total; i += gridDim.x * 256) {
        const int r = i / C, c = i % C;
        const float v = (r < validR) ? src[(size_t)r * srcld + c] : 0.f;
        wsplit(dhi, dlo, (size_t)r * dstld + coloff + c, v);
    }
}

// ============================================================
// init: zero c1,c2; A2 pair = 0; A1 pair = [split(E[BOS]) | 0]
// ============================================================
__global__ __launch_bounds__(256)
void init_kernel(_Float16* __restrict__ a1h, _Float16* __restrict__ a1l,
                 _Float16* __restrict__ a2h, _Float16* __restrict__ a2l,
                 float* __restrict__ c1, float* __restrict__ c2,
                 const float* __restrict__ E)
{
    const int idx = blockIdx.x * 256 + threadIdx.x;   // grid covers 512*1536
    if (idx < Bsz * K1) {
        const int col = idx % K1;
        const float v = (col < Em) ? E[(size_t)BOS * Em + col] : 0.f;
        wsplit(a1h, a1l, idx, v);
    }
    if (idx < Bsz * K2) wsplit(a2h, a2l, idx, 0.f);
    if (idx < Bsz * Hh) { c1[idx] = 0.f; c2[idx] = 0.f; }
}

// f_mean[b,a] = mean_k f_att[b,k,a]
__global__ __launch_bounds__(256)
void fmean_kernel(const float* __restrict__ f_att, float* __restrict__ f_mean)
{
    const int b = blockIdx.x;
    for (int a = threadIdx.x; a < Aa; a += 256) {
        float s = 0.f;
        for (int k = 0; k < Kf; ++k) s += f_att[((size_t)b * Kf + k) * Aa + a];
        f_mean[(size_t)b * Aa + a] = s * (1.0f / 36.0f);
    }
}

// LSTM cell elementwise; h written as fp16 split pair(s).
// Dest 2 is optional (pass nullptr) — used to propagate h1 into the A1 buffer.
__global__ __launch_bounds__(256)
void lstm_cell_kernel(const float* __restrict__ g, float* __restrict__ c,
                      _Float16* __restrict__ hhi, _Float16* __restrict__ hlo,
                      int hld, int hoff,
                      _Float16* __restrict__ h2hi, _Float16* __restrict__ h2lo,
                      int h2ld, int h2off)
{
    const int idx = blockIdx.x * 256 + threadIdx.x;   // < B*H
    const int b = idx >> 9, h = idx & 511;
    const float* gb = g + (size_t)b * 2048;
    const float gi = gb[h], gf = gb[512 + h], gc = gb[1024 + h], go = gb[1536 + h];
    const float cv = sigm(gf) * c[idx] + sigm(gi) * tanhf(gc);
    c[idx] = cv;
    const float hv = sigm(go) * tanhf(cv);
    wsplit(hhi, hlo, (size_t)b * hld + hoff + h, hv);
    if (h2hi) wsplit(h2hi, h2lo, (size_t)b * h2ld + h2off + h, hv);
}

// e[b,k] = sum_a wa2[a]*tanh(att_f[b,k,a] + q[b,a]) + ba2   (one wave per (b,k))
__global__ __launch_bounds__(256)
void attn_e_kernel(const float* __restrict__ att_f, const float* __restrict__ q,
                   const float* __restrict__ wa2, const float* __restrict__ ba2,
                   float* __restrict__ e)
{
    const int wid = blockIdx.x * 4 + (threadIdx.x >> 6);
    const int lane = threadIdx.x & 63;
    const int b = wid / Kf, k = wid % Kf;
    const float* pf = att_f + ((size_t)b * Kf + k) * Aa;
    const float* pq = q + (size_t)b * Aa;
    float s = 0.f;
    for (int j = 0; j < Aa; j += 64) {
        const int a = j + lane;
        s += tanhf(pf[a] + pq[a]) * wa2[a];
    }
    #pragma unroll
    for (int off = 32; off; off >>= 1) s += __shfl_down(s, off);
    if (lane == 0) e[wid] = s + ba2[0];
}

// softmax over k then ctx[b,a] = sum_k alpha[k]*f_att[b,k,a]; ctx -> A2 cols [512,1024)
__global__ __launch_bounds__(256)
void softmax_ctx_kernel(const float* __restrict__ e, const float* __restrict__ f_att,
                        _Float16* __restrict__ a2h, _Float16* __restrict__ a2l)
{
    const int b = blockIdx.x;
    const int tid = threadIdx.x;
    __shared__ float se[Kf];
    __shared__ float wk[Kf];
    if (tid < Kf) se[tid] = e[(size_t)b * Kf + tid];
    __syncthreads();
    if (tid < Kf) {
        float mx = -INFINITY;
        for (int k = 0; k < Kf; ++k) mx = fmaxf(mx, se[k]);
        float s = 0.f;
        for (int k = 0; k < Kf; ++k) s += expf(se[k] - mx);
        wk[tid] = expf(se[tid] - mx) / s;
    }
    __syncthreads();
    for (int a = tid; a < Aa; a += 256) {
        float acc = 0.f;
        for (int k = 0; k < Kf; ++k)
            acc = fmaf(wk[k], f_att[((size_t)b * Kf + k) * Aa + a], acc);
        wsplit(a2h, a2l, (size_t)b * K2 + Hh + a, acc);
    }
}

// argmax over vocab (first-index tie-break) + embed gather -> A1 split cols [0,300)
__global__ __launch_bounds__(256)
void argmax_embed_kernel(const float* __restrict__ logits, const float* __restrict__ E,
                         _Float16* __restrict__ a1h, _Float16* __restrict__ a1l,
                         int* __restrict__ out, int t)
{
    const int b = blockIdx.x;
    const int tid = threadIdx.x;
    float best = -INFINITY;
    int bi = Vv;
    for (int j = tid; j < Vv; j += 256) {
        const float v = logits[(size_t)b * Vv + j];
        if (v > best) { best = v; bi = j; }
    }
    __shared__ float sv[256];
    __shared__ int   si[256];
    sv[tid] = best; si[tid] = bi;
    __syncthreads();
    for (int s = 128; s > 0; s >>= 1) {
        if (tid < s) {
            const float v2 = sv[tid + s];
            const int   i2 = si[tid + s];
            if (v2 > sv[tid] || (v2 == sv[tid] && i2 < si[tid])) { sv[tid] = v2; si[tid] = i2; }
        }
        __syncthreads();
    }
    const int idx = si[0];
    if (tid == 0) out[(size_t)b * TSTEPS + t] = idx;
    for (int d = tid; d < Em; d += 256)
        wsplit(a1h, a1l, (size_t)b * K1 + d, E[(size_t)idx * Em + d]);
}

// ============================================================
// host side
// ============================================================
static inline void conv(hipStream_t s, const float* src, int srcld, int validR,
                        _Float16* dhi, _Float16* dlo, int dstld, int coloff, int R, int C)
{
    int blocks = CDIV(R * C, 256); if (blocks > 2048) blocks = 2048;
    split_convert<<<dim3(blocks), dim3(256), 0, s>>>(src, srcld, validR, dhi, dlo, dstld, coloff, R, C);
}

extern "C" void kernel_launch(void* const* d_in, const int* in_sizes, int n_in,
                              void* d_out, int out_size, void* d_ws, size_t ws_size,
                              hipStream_t stream)
{
    const float* feats = (const float*)d_in[0];
    const float* Wp    = (const float*)d_in[1];
    const float* bp    = (const float*)d_in[2];
    const float* E     = (const float*)d_in[3];
    const float* Wih1  = (const float*)d_in[4];
    const float* Whh1  = (const float*)d_in[5];
    const float* bih1  = (const float*)d_in[6];
    const float* bhh1  = (const float*)d_in[7];
    const float* Wih2  = (const float*)d_in[8];
    const float* Whh2  = (const float*)d_in[9];
    const float* bih2  = (const float*)d_in[10];
    const float* bhh2  = (const float*)d_in[11];
    const float* Wa1   = (const float*)d_in[12];
    const float* ba1   = (const float*)d_in[13];
    const float* wa2   = (const float*)d_in[14];
    const float* ba2   = (const float*)d_in[15];
    const float* Wo    = (const float*)d_in[16];
    const float* bo    = (const float*)d_in[17];
    int* out = (int*)d_out;
    (void)in_sizes; (void)n_in; (void)out_size; (void)ws_size;

    uint8_t* w = (uint8_t*)d_ws;
    size_t off = 0;
    auto alloc = [&](size_t bytes) { void* p = w + off; off = (off + bytes + 255) & ~(size_t)255; return p; };

    float*     f_att  = (float*)alloc(18432ull * 512 * 4);
    float*     att_f  = (float*)alloc(18432ull * 512 * 4);
    float*     f_mean = (float*)alloc(512ull * 512 * 4);
    _Float16*  fmh    = (_Float16*)alloc(512ull * 512 * 2);
    _Float16*  fml    = (_Float16*)alloc(512ull * 512 * 2);
    _Float16*  wph    = (_Float16*)alloc(512ull * 2048 * 2);
    _Float16*  wpl    = (_Float16*)alloc(512ull * 2048 * 2);
    _Float16*  w1ph   = (_Float16*)alloc(2048ull * K1 * 2);
    _Float16*  w1pl   = (_Float16*)alloc(2048ull * K1 * 2);
    _Float16*  w1ch   = (_Float16*)alloc(2048ull * 512 * 2);
    _Float16*  w1cl   = (_Float16*)alloc(2048ull * 512 * 2);
    _Float16*  w2ph   = (_Float16*)alloc(2048ull * K2 * 2);
    _Float16*  w2pl   = (_Float16*)alloc(2048ull * K2 * 2);
    _Float16*  wahh   = (_Float16*)alloc(512ull * 512 * 2);
    _Float16*  wahl   = (_Float16*)alloc(512ull * 512 * 2);
    _Float16*  wafh   = (_Float16*)alloc(512ull * 512 * 2);
    _Float16*  wafl   = (_Float16*)alloc(512ull * 512 * 2);
    _Float16*  woh    = (_Float16*)alloc((size_t)VvP * 512 * 2);
    _Float16*  wol    = (_Float16*)alloc((size_t)VvP * 512 * 2);
    float*     g1c    = (float*)alloc(512ull * 2048 * 4);
    _Float16*  a1h    = (_Float16*)alloc(512ull * K1 * 2);
    _Float16*  a1l    = (_Float16*)alloc(512ull * K1 * 2);
    _Float16*  a2h    = (_Float16*)alloc(512ull * K2 * 2);
    _Float16*  a2l    = (_Float16*)alloc(512ull * K2 * 2);
    float*     c1     = (float*)alloc(512ull * 512 * 4);
    float*     c2     = (float*)alloc(512ull * 512 * 4);
    float*     gbuf   = (float*)alloc(512ull * 2048 * 4);
    float*     qbuf   = (float*)alloc(512ull * 512 * 4);
    float*     evec   = (float*)alloc(512ull * Kf * 4);
    float*     logits = (float*)alloc(512ull * Vv * 4);

    // ---- weight conversions (run every launch; deterministic) ----
    conv(stream, Wp,          Dd,      512,   wph,  wpl,  2048, 0,    512,  2048);
    conv(stream, Wih1,        Em + Aa, 2048,  w1ph, w1pl, K1,   0,    2048, Em);
    conv(stream, Whh1,        Hh,      2048,  w1ph, w1pl, K1,   Em,   2048, 512);
    conv(stream, Wih1,        Em + Aa, 0,     w1ph, w1pl, K1,   812,  2048, 20);   // zero pad cols
    conv(stream, Wih1 + Em,   Em + Aa, 2048,  w1ch, w1cl, 512,  0,    2048, 512);
    conv(stream, Wih2,        Hh + Aa, 2048,  w2ph, w2pl, K2,   0,    2048, 1024);
    conv(stream, Whh2,        Hh,      2048,  w2ph, w2pl, K2,   1024, 2048, 512);
    conv(stream, Wa1,         Hh + Aa, 512,   wahh, wahl, 512,  0,    512,  512);
    conv(stream, Wa1 + Hh,    Hh + Aa, 512,   wafh, wafl, 512,  0,    512,  512);
    conv(stream, Wo,          Hh,      Vv,    woh,  wol,  512,  0,    VvP,  512);

    init_kernel<<<dim3(CDIV(Bsz * K2, 256)), dim3(256), 0, stream>>>(a1h, a1l, a2h, a2l, c1, c2, E);

    // ---- precompute GEMMs ----
    // f_att = feats @ Wp^T + bp    (18432 x 512, K=2048)
    gemm_sp<128, 128, true><<<dim3(CDIV(512, 128), 18432 / 128), 256, 0, stream>>>(
        feats, nullptr, nullptr, Dd, wph, wpl, 2048, f_att, 512, 512, 2048, bp, nullptr, nullptr);
    fmean_kernel<<<dim3(Bsz), dim3(256), 0, stream>>>(f_att, f_mean);
    conv(stream, f_mean, 512, 512, fmh, fml, 512, 0, 512, 512);
    // g1c = f_mean @ Wih1[:,Em:]^T + bih1 + bhh1   (512 x 2048, K=512)
    gemm_sp<64, 64, false><<<dim3(2048 / 64, 512 / 64), 256, 0, stream>>>(
        nullptr, fmh, fml, 512, w1ch, w1cl, 512, g1c, 2048, 2048, 512, bih1, bhh1, nullptr);
    // att_f = f_att @ Wa1[:,H:]^T + ba1   (18432 x 512, K=512)
    gemm_sp<128, 128, true><<<dim3(CDIV(512, 128), 18432 / 128), 256, 0, stream>>>(
        f_att, nullptr, nullptr, 512, wafh, wafl, 512, att_f, 512, 512, 512, ba1, nullptr, nullptr);

    // ---- decode loop ----
    for (int t = 0; t < TSTEPS; ++t) {
        // g1 = A1 @ W1p^T + g1c   (512 x 2048, K=832)
        gemm_sp<64, 64, false><<<dim3(2048 / 64, 512 / 64), 256, 0, stream>>>(
            nullptr, a1h, a1l, K1, w1ph, w1pl, K1, gbuf, 2048, 2048, K1, nullptr, nullptr, g1c);
        // h1 -> A2 cols [0,512)  AND  A1 cols [300,812)  (recurrent input!)
        lstm_cell_kernel<<<dim3(Bsz * Hh / 256), dim3(256), 0, stream>>>(
            gbuf, c1, a2h, a2l, K2, 0, a1h, a1l, K1, Em);
        // q = h1 @ Wa1[:,:H]^T   (512 x 512, K=512); h1 = A2 cols [0,512)
        gemm_sp<64, 64, false><<<dim3(512 / 64, 512 / 64), 256, 0, stream>>>(
            nullptr, a2h, a2l, K2, wahh, wahl, 512, qbuf, 512, 512, 512, nullptr, nullptr, nullptr);
        attn_e_kernel<<<dim3(Bsz * Kf / 4), dim3(256), 0, stream>>>(att_f, qbuf, wa2, ba2, evec);
        softmax_ctx_kernel<<<dim3(Bsz), dim3(256), 0, stream>>>(evec, f_att, a2h, a2l);
        // g2 = A2 @ W2p^T + bih2 + bhh2   (512 x 2048, K=1536)
        gemm_sp<64, 64, false><<<dim3(2048 / 64, 512 / 64), 256, 0, stream>>>(
            nullptr, a2h, a2l, K2, w2ph, w2pl, K2, gbuf, 2048, 2048, K2, bih2, bhh2, nullptr);
        lstm_cell_kernel<<<dim3(Bsz * Hh / 256), dim3(256), 0, stream>>>(
            gbuf, c2, a2h, a2l, K2, 1024, nullptr, nullptr, 0, 0);
        // logits = h2 @ Wo^T + bo   (512 x 10000, K=512); h2 = A2 cols [1024,1536)
        gemm_sp<128, 128, false><<<dim3(CDIV(Vv, 128), 512 / 128), 256, 0, stream>>>(
            nullptr, a2h + 1024, a2l + 1024, K2, woh, wol, 512, logits, Vv, Vv, 512, bo, nullptr, nullptr);
        argmax_embed_kernel<<<dim3(Bsz), dim3(256), 0, stream>>>(logits, E, a1h, a1l, out, t);
    }
}

// Round 4
// 3604.013 us; speedup vs baseline: 2.0952x; 1.3312x over previous
//
#include <hip/hip_runtime.h>
#include <math.h>
#include <stdint.h>

// ---- problem dims ----
constexpr int Bsz = 512, Kf = 36, Dd = 2048, Aa = 512, Hh = 512, Em = 300;
constexpr int Vv = 10000, TSTEPS = 19, BOS = 1;
constexpr int K1 = 832;          // padded Em+Hh (812 -> 832, mult of 64)
constexpr int K2 = 1536;         // h1|ctx|h2
constexpr int VvP = 10112;       // vocab rows padded (mult of 64)
constexpr float SPLIT_S  = 2048.0f;
constexpr float SPLIT_IS = 1.0f / 2048.0f;

#define CDIV(a,b) (((a)+(b)-1)/(b))

typedef _Float16 f16x8 __attribute__((ext_vector_type(8)));
typedef float    f32x4 __attribute__((ext_vector_type(4)));

typedef const unsigned int GU __attribute__((address_space(1)));
typedef unsigned int       LU __attribute__((address_space(3)));

__device__ __forceinline__ void gload16(const void* g, void* l) {
    __builtin_amdgcn_global_load_lds((GU*)g, (LU*)l, 16, 0, 0);
}

template<int N> __device__ __forceinline__ void wait_vm() {
    if constexpr (N == 0)       asm volatile("s_waitcnt vmcnt(0)" ::: "memory");
    else if constexpr (N == 4)  asm volatile("s_waitcnt vmcnt(4)" ::: "memory");
    else if constexpr (N == 6)  asm volatile("s_waitcnt vmcnt(6)" ::: "memory");
    else if constexpr (N == 8)  asm volatile("s_waitcnt vmcnt(8)" ::: "memory");
    else if constexpr (N == 12) asm volatile("s_waitcnt vmcnt(12)" ::: "memory");
    else if constexpr (N == 16) asm volatile("s_waitcnt vmcnt(16)" ::: "memory");
    else static_assert(N == 0, "unsupported vmcnt literal");
}
#define WAIT_LGKM asm volatile("s_waitcnt lgkmcnt(0)" ::: "memory")
#define SB0 __builtin_amdgcn_sched_barrier(0)
#define BAR __builtin_amdgcn_s_barrier()

__device__ __forceinline__ float sigm(float v) { return 1.0f / (1.0f + expf(-v)); }

__device__ __forceinline__ void wsplit(_Float16* __restrict__ hi, _Float16* __restrict__ lo,
                                       size_t idx, float v) {
    _Float16 h = (_Float16)v;
    hi[idx] = h;
    lo[idx] = (_Float16)((v - (float)h) * SPLIT_S);
}

// ============================================================
// Split-fp16 MFMA GEMM with double-buffered LDS + counted-vmcnt prefetch:
//   C[M,N] = A[M,K] @ B[N,K]^T (+bias1+bias2+addC)
// A: fp32 (AF32, reg-prefetch + in-kernel split; requires K/BK even) or
//    pre-split f16 hi/lo (global_load_lds direct).
// B: pre-split f16 hi/lo, row-major [N][ldb].
// ============================================================
template<int BM, int BN, int BK, bool AF32>
__global__ __launch_bounds__(256)
void gemm_sp(const float* __restrict__ Af,
             const _Float16* __restrict__ Ahi, const _Float16* __restrict__ Alo, int lda,
             const _Float16* __restrict__ Bhi, const _Float16* __restrict__ Blo, int ldb,
             float* __restrict__ C, int ldc, int N, int K,
             const float* __restrict__ bias1, const float* __restrict__ bias2,
             const float* __restrict__ addC)
{
    constexpr int WM = BM / 2, WN = BN / 2;
    constexpr int MF = WM / 16, NF = WN / 16;
    constexpr int PA  = BK / 8;                 // 8-half k-planes per tile
    constexpr int PSA = BM * 8 + 8;             // plane stride (halfs)
    constexpr int PSB = BN * 8 + 8;
    constexpr int SZA = PA * PSA, SZB = PA * PSB;
    constexpr int OAH = 0, OAL = SZA, OBH = 2 * SZA, OBL = 2 * SZA + SZB;
    constexpr int BUF = 2 * SZA + 2 * SZB;
    constexpr int NCHA = BM * BK / 2048;        // 16B chunks per thread (A)
    constexpr int NCHB = BN * BK / 2048;
    constexpr int LW = 2 * NCHA + 2 * NCHB;     // vm ops per thread per tile
    __shared__ _Float16 sm[2 * BUF];

    const int t    = threadIdx.x;
    const int lane = t & 63;
    const int w    = t >> 6;
    const int wr   = w >> 1, wc = w & 1;
    const int m0   = blockIdx.y * BM, n0 = blockIdx.x * BN;
    const int l15  = lane & 15, l4 = lane >> 4;

    f32x4 acch[MF][NF];
    f32x4 accm[MF][NF];
    #pragma unroll
    for (int m = 0; m < MF; ++m)
        #pragma unroll
        for (int n = 0; n < NF; ++n) {
            acch[m][n] = (f32x4){0.f, 0.f, 0.f, 0.f};
            accm[m][n] = (f32x4){0.f, 0.f, 0.f, 0.f};
        }

    const int nkt = K / BK;

    auto stageB = [&](int bufo, int kt) {
        #pragma unroll
        for (int i = 0; i < NCHB; ++i) {
            const int q  = i * 256 + t;
            const int p  = q / BN, r = q % BN;
            const int qw = i * 256 + (t & ~63);
            const int pu = qw / BN, ru = qw % BN;
            const size_t goff = (size_t)(n0 + r) * ldb + kt * BK + p * 8;
            gload16(Bhi + goff, &sm[bufo + OBH + pu * PSB + ru * 8]);
            gload16(Blo + goff, &sm[bufo + OBL + pu * PSB + ru * 8]);
        }
    };
    auto stageA16 = [&](int bufo, int kt) {
        #pragma unroll
        for (int i = 0; i < NCHA; ++i) {
            const int q  = i * 256 + t;
            const int p  = q / BM, r = q % BM;
            const int qw = i * 256 + (t & ~63);
            const int pu = qw / BM, ru = qw % BM;
            const size_t goff = (size_t)(m0 + r) * lda + kt * BK + p * 8;
            gload16(Ahi + goff, &sm[bufo + OAH + pu * PSA + ru * 8]);
            gload16(Alo + goff, &sm[bufo + OAL + pu * PSA + ru * 8]);
        }
    };
    auto issueA = [&](float4 (&rd)[NCHA][2], int kt) {
        #pragma unroll
        for (int i = 0; i < NCHA; ++i) {
            const int q = i * 256 + t;
            const int p = q / BM, r = q % BM;
            const float* src = Af + (size_t)(m0 + r) * lda + kt * BK + p * 8;
            rd[i][0] = *(const float4*)src;
            rd[i][1] = *(const float4*)(src + 4);
        }
    };
    auto writeA = [&](int bufo, float4 (&rd)[NCHA][2]) {
        #pragma unroll
        for (int i = 0; i < NCHA; ++i) {
            const int q = i * 256 + t;
            const int p = q / BM, r = q % BM;
            const float f[8] = {rd[i][0].x, rd[i][0].y, rd[i][0].z, rd[i][0].w,
                                rd[i][1].x, rd[i][1].y, rd[i][1].z, rd[i][1].w};
            f16x8 hi, lo;
            #pragma unroll
            for (int j = 0; j < 8; ++j) {
                _Float16 h = (_Float16)f[j];
                hi[j] = h;
                lo[j] = (_Float16)((f[j] - (float)h) * SPLIT_S);
            }
            *(f16x8*)&sm[bufo + OAH + p * PSA + r * 8] = hi;
            *(f16x8*)&sm[bufo + OAL + p * PSA + r * 8] = lo;
        }
    };
    auto compute = [&](int bufo) {
        #pragma unroll
        for (int s = 0; s < BK / 32; ++s) {
            f16x8 ah[MF], al[MF], bh[NF], bl[NF];
            const int pl = s * 4 + l4;
            #pragma unroll
            for (int m = 0; m < MF; ++m) {
                const int row = wr * WM + m * 16 + l15;
                ah[m] = *(const f16x8*)&sm[bufo + OAH + pl * PSA + row * 8];
                al[m] = *(const f16x8*)&sm[bufo + OAL + pl * PSA + row * 8];
            }
            #pragma unroll
            for (int n = 0; n < NF; ++n) {
                const int row = wc * WN + n * 16 + l15;
                bh[n] = *(const f16x8*)&sm[bufo + OBH + pl * PSB + row * 8];
                bl[n] = *(const f16x8*)&sm[bufo + OBL + pl * PSB + row * 8];
            }
            #pragma unroll
            for (int m = 0; m < MF; ++m)
                #pragma unroll
                for (int n = 0; n < NF; ++n) {
                    acch[m][n] = __builtin_amdgcn_mfma_f32_16x16x32_f16(ah[m], bh[n], acch[m][n], 0, 0, 0);
                    accm[m][n] = __builtin_amdgcn_mfma_f32_16x16x32_f16(ah[m], bl[n], accm[m][n], 0, 0, 0);
                    accm[m][n] = __builtin_amdgcn_mfma_f32_16x16x32_f16(al[m], bh[n], accm[m][n], 0, 0, 0);
                }
        }
    };

    if constexpr (AF32) {
        // K/BK must be even at all AF32 call sites.
        float4 rA[NCHA][2], rB[NCHA][2];
        issueA(rA, 0); stageB(0, 0);
        for (int kt = 0; kt < nkt; kt += 2) {
            // ---- tile kt (buffer 0, regs rA; prefetch kt+1 into rB/buf1) ----
            issueA(rB, kt + 1); stageB(BUF, kt + 1);
            wait_vm<LW>(); SB0;
            writeA(0, rA);
            WAIT_LGKM; SB0;
            BAR; SB0;
            compute(0);
            SB0; WAIT_LGKM; BAR; SB0;
            // ---- tile kt+1 (buffer 1, regs rB; prefetch kt+2 into rA/buf0) ----
            if (kt + 2 < nkt) { issueA(rA, kt + 2); stageB(0, kt + 2); wait_vm<LW>(); }
            else              { wait_vm<0>(); }
            SB0;
            writeA(BUF, rB);
            WAIT_LGKM; SB0;
            BAR; SB0;
            compute(BUF);
            SB0; WAIT_LGKM; BAR; SB0;
        }
    } else {
        stageA16(0, 0); stageB(0, 0);
        for (int kt = 0; kt < nkt; ++kt) {
            const int bufc = (kt & 1) ? BUF : 0;
            const int bufn = BUF - bufc;
            if (kt + 1 < nkt) { stageA16(bufn, kt + 1); stageB(bufn, kt + 1); wait_vm<LW>(); }
            else              { wait_vm<0>(); }
            SB0;
            BAR; SB0;
            compute(bufc);
            SB0; WAIT_LGKM; BAR; SB0;
        }
    }

    // ---- epilogue: C = acch + accm/S (+biases +addC) ----
    #pragma unroll
    for (int m = 0; m < MF; ++m) {
        const int rowb = m0 + wr * WM + m * 16 + l4 * 4;
        #pragma unroll
        for (int n = 0; n < NF; ++n) {
            const int col = n0 + wc * WN + n * 16 + l15;
            if (col < N) {
                float bb = 0.f;
                if (bias1) bb += bias1[col];
                if (bias2) bb += bias2[col];
                #pragma unroll
                for (int r = 0; r < 4; ++r) {
                    const size_t idx = (size_t)(rowb + r) * ldc + col;
                    float v = acch[m][n][r] + accm[m][n][r] * SPLIT_IS + bb;
                    if (addC) v += addC[idx];
                    C[idx] = v;
                }
            }
        }
    }
}

// ============================================================
// weight split-convert
// ============================================================
__global__ __launch_bounds__(256)
void split_convert(const float* __restrict__ src, int srcld, int validR,
                   _Float16* __restrict__ dhi, _Float16* __restrict__ dlo,
                   int dstld, int coloff, int R, int C)
{
    const int total = R * C;
    for (int i = blockIdx.x * 256 + threadIdx.x; i < total; i += gridDim.x * 256) {
        const int r = i / C, c = i % C;
        const float v = (r < validR) ? src[(size_t)r * srcld + c] : 0.f;
        wsplit(dhi, dlo, (size_t)r * dstld + coloff + c, v);
    }
}

__global__ __launch_bounds__(256)
void init_kernel(_Float16* __restrict__ a1h, _Float16* __restrict__ a1l,
                 _Float16* __restrict__ a2h, _Float16* __restrict__ a2l,
                 float* __restrict__ c1, float* __restrict__ c2,
                 const float* __restrict__ E)
{
    const int idx = blockIdx.x * 256 + threadIdx.x;   // grid covers 512*1536
    if (idx < Bsz * K1) {
        const int col = idx % K1;
        const float v = (col < Em) ? E[(size_t)BOS * Em + col] : 0.f;
        wsplit(a1h, a1l, idx, v);
    }
    if (idx < Bsz * K2) wsplit(a2h, a2l, idx, 0.f);
    if (idx < Bsz * Hh) { c1[idx] = 0.f; c2[idx] = 0.f; }
}

// f_mean (fp32 + split pair)
__global__ __launch_bounds__(256)
void fmean_kernel(const float* __restrict__ f_att, float* __restrict__ f_mean,
                  _Float16* __restrict__ fmh, _Float16* __restrict__ fml)
{
    const int b = blockIdx.x;
    for (int a = threadIdx.x; a < Aa; a += 256) {
        float s = 0.f;
        for (int k = 0; k < Kf; ++k) s += f_att[((size_t)b * Kf + k) * Aa + a];
        const float v = s * (1.0f / 36.0f);
        f_mean[(size_t)b * Aa + a] = v;
        wsplit(fmh, fml, (size_t)b * Aa + a, v);
    }
}

// LSTM cell elementwise; h written as fp16 split pair(s).
__global__ __launch_bounds__(256)
void lstm_cell_kernel(const float* __restrict__ g, float* __restrict__ c,
                      _Float16* __restrict__ hhi, _Float16* __restrict__ hlo,
                      int hld, int hoff,
                      _Float16* __restrict__ h2hi, _Float16* __restrict__ h2lo,
                      int h2ld, int h2off)
{
    const int idx = blockIdx.x * 256 + threadIdx.x;   // < B*H
    const int b = idx >> 9, h = idx & 511;
    const float* gb = g + (size_t)b * 2048;
    const float gi = gb[h], gf = gb[512 + h], gc = gb[1024 + h], go = gb[1536 + h];
    const float cv = sigm(gf) * c[idx] + sigm(gi) * tanhf(gc);
    c[idx] = cv;
    const float hv = sigm(go) * tanhf(cv);
    wsplit(hhi, hlo, (size_t)b * hld + hoff + h, hv);
    if (h2hi) wsplit(h2hi, h2lo, (size_t)b * h2ld + h2off + h, hv);
}

// Fused attention: e scores (tanh dot), softmax over k, ctx -> A2 cols [512,1024)
// One block per b; 4 waves; numerics identical to the previous split kernels.
__global__ __launch_bounds__(256)
void attn_fused(const float* __restrict__ att_f, const float* __restrict__ q,
                const float* __restrict__ wa2, const float* __restrict__ ba2,
                const float* __restrict__ f_att,
                _Float16* __restrict__ a2h, _Float16* __restrict__ a2l)
{
    const int b = blockIdx.x, tid = threadIdx.x;
    const int w = tid >> 6, lane = tid & 63;
    __shared__ float se[Kf];
    __shared__ float wk[Kf];
    const float* pq = q + (size_t)b * Aa;
    for (int k = w; k < Kf; k += 4) {
        const float* pf = att_f + ((size_t)b * Kf + k) * Aa;
        float s = 0.f;
        #pragma unroll
        for (int j = 0; j < Aa; j += 64) {
            const int a = j + lane;
            s += tanhf(pf[a] + pq[a]) * wa2[a];
        }
        #pragma unroll
        for (int off = 32; off; off >>= 1) s += __shfl_down(s, off);
        if (lane == 0) se[k] = s + ba2[0];
    }
    __syncthreads();
    if (tid < Kf) {
        float mx = -INFINITY;
        for (int k = 0; k < Kf; ++k) mx = fmaxf(mx, se[k]);
        float ssum = 0.f;
        for (int k = 0; k < Kf; ++k) ssum += expf(se[k] - mx);
        wk[tid] = expf(se[tid] - mx) / ssum;
    }
    __syncthreads();
    for (int a = tid; a < Aa; a += 256) {
        float acc = 0.f;
        for (int k = 0; k < Kf; ++k)
            acc = fmaf(wk[k], f_att[((size_t)b * Kf + k) * Aa + a], acc);
        wsplit(a2h, a2l, (size_t)b * K2 + Hh + a, acc);
    }
}

// argmax over vocab (first-index tie-break) + embed gather -> A1 split cols [0,300)
__global__ __launch_bounds__(256)
void argmax_embed_kernel(const float* __restrict__ logits, const float* __restrict__ E,
                         _Float16* __restrict__ a1h, _Float16* __restrict__ a1l,
                         int* __restrict__ out, int t)
{
    const int b = blockIdx.x;
    const int tid = threadIdx.x;
    float best = -INFINITY;
    int bi = Vv;
    for (int j = tid; j < Vv; j += 256) {
        const float v = logits[(size_t)b * Vv + j];
        if (v > best) { best = v; bi = j; }
    }
    __shared__ float sv[256];
    __shared__ int   si[256];
    sv[tid] = best; si[tid] = bi;
    __syncthreads();
    for (int s = 128; s > 0; s >>= 1) {
        if (tid < s) {
            const float v2 = sv[tid + s];
            const int   i2 = si[tid + s];
            if (v2 > sv[tid] || (v2 == sv[tid] && i2 < si[tid])) { sv[tid] = v2; si[tid] = i2; }
        }
        __syncthreads();
    }
    const int idx = si[0];
    if (tid == 0) out[(size_t)b * TSTEPS + t] = idx;
    for (int d = tid; d < Em; d += 256)
        wsplit(a1h, a1l, (size_t)b * K1 + d, E[(size_t)idx * Em + d]);
}

// ============================================================
// host side
// ============================================================
static inline void conv(hipStream_t s, const float* src, int srcld, int validR,
                        _Float16* dhi, _Float16* dlo, int dstld, int coloff, int R, int C)
{
    int blocks = CDIV(R * C, 256); if (blocks > 2048) blocks = 2048;
    split_convert<<<dim3(blocks), dim3(256), 0, s>>>(src, srcld, validR, dhi, dlo, dstld, coloff, R, C);
}

extern "C" void kernel_launch(void* const* d_in, const int* in_sizes, int n_in,
                              void* d_out, int out_size, void* d_ws, size_t ws_size,
                              hipStream_t stream)
{
    const float* feats = (const float*)d_in[0];
    const float* Wp    = (const float*)d_in[1];
    const float* bp    = (const float*)d_in[2];
    const float* E     = (const float*)d_in[3];
    const float* Wih1  = (const float*)d_in[4];
    const float* Whh1  = (const float*)d_in[5];
    const float* bih1  = (const float*)d_in[6];
    const float* bhh1  = (const float*)d_in[7];
    const float* Wih2  = (const float*)d_in[8];
    const float* Whh2  = (const float*)d_in[9];
    const float* bih2  = (const float*)d_in[10];
    const float* bhh2  = (const float*)d_in[11];
    const float* Wa1   = (const float*)d_in[12];
    const float* ba1   = (const float*)d_in[13];
    const float* wa2   = (const float*)d_in[14];
    const float* ba2   = (const float*)d_in[15];
    const float* Wo    = (const float*)d_in[16];
    const float* bo    = (const float*)d_in[17];
    int* out = (int*)d_out;
    (void)in_sizes; (void)n_in; (void)out_size; (void)ws_size;

    uint8_t* w = (uint8_t*)d_ws;
    size_t off = 0;
    auto alloc = [&](size_t bytes) { void* p = w + off; off = (off + bytes + 255) & ~(size_t)255; return p; };

    float*     f_att  = (float*)alloc(18432ull * 512 * 4);
    float*     att_f  = (float*)alloc(18432ull * 512 * 4);
    float*     f_mean = (float*)alloc(512ull * 512 * 4);
    _Float16*  fmh    = (_Float16*)alloc(512ull * 512 * 2);
    _Float16*  fml    = (_Float16*)alloc(512ull * 512 * 2);
    _Float16*  wph    = (_Float16*)alloc(512ull * 2048 * 2);
    _Float16*  wpl    = (_Float16*)alloc(512ull * 2048 * 2);
    _Float16*  w1ph   = (_Float16*)alloc(2048ull * K1 * 2);
    _Float16*  w1pl   = (_Float16*)alloc(2048ull * K1 * 2);
    _Float16*  w1ch   = (_Float16*)alloc(2048ull * 512 * 2);
    _Float16*  w1cl   = (_Float16*)alloc(2048ull * 512 * 2);
    _Float16*  w2ph   = (_Float16*)alloc(2048ull * K2 * 2);
    _Float16*  w2pl   = (_Float16*)alloc(2048ull * K2 * 2);
    _Float16*  wahh   = (_Float16*)alloc(512ull * 512 * 2);
    _Float16*  wahl   = (_Float16*)alloc(512ull * 512 * 2);
    _Float16*  wafh   = (_Float16*)alloc(512ull * 512 * 2);
    _Float16*  wafl   = (_Float16*)alloc(512ull * 512 * 2);
    _Float16*  woh    = (_Float16*)alloc((size_t)VvP * 512 * 2);
    _Float16*  wol    = (_Float16*)alloc((size_t)VvP * 512 * 2);
    float*     g1c    = (float*)alloc(512ull * 2048 * 4);
    _Float16*  a1h    = (_Float16*)alloc(512ull * K1 * 2);
    _Float16*  a1l    = (_Float16*)alloc(512ull * K1 * 2);
    _Float16*  a2h    = (_Float16*)alloc(512ull * K2 * 2);
    _Float16*  a2l    = (_Float16*)alloc(512ull * K2 * 2);
    float*     c1     = (float*)alloc(512ull * 512 * 4);
    float*     c2     = (float*)alloc(512ull * 512 * 4);
    float*     gbuf   = (float*)alloc(512ull * 2048 * 4);
    float*     qbuf   = (float*)alloc(512ull * 512 * 4);
    float*     logits = (float*)alloc(512ull * Vv * 4);

    // ---- weight conversions ----
    conv(stream, Wp,          Dd,      512,   wph,  wpl,  2048, 0,    512,  2048);
    conv(stream, Wih1,        Em + Aa, 2048,  w1ph, w1pl, K1,   0,    2048, Em);
    conv(stream, Whh1,        Hh,      2048,  w1ph, w1pl, K1,   Em,   2048, 512);
    conv(stream, Wih1,        Em + Aa, 0,     w1ph, w1pl, K1,   812,  2048, 20);   // zero pad cols
    conv(stream, Wih1 + Em,   Em + Aa, 2048,  w1ch, w1cl, 512,  0,    2048, 512);
    conv(stream, Wih2,        Hh + Aa, 2048,  w2ph, w2pl, K2,   0,    2048, 1024);
    conv(stream, Whh2,        Hh,      2048,  w2ph, w2pl, K2,   1024, 2048, 512);
    conv(stream, Wa1,         Hh + Aa, 512,   wahh, wahl, 512,  0,    512,  512);
    conv(stream, Wa1 + Hh,    Hh + Aa, 512,   wafh, wafl, 512,  0,    512,  512);
    conv(stream, Wo,          Hh,      Vv,    woh,  wol,  512,  0,    VvP,  512);

    init_kernel<<<dim3(CDIV(Bsz * K2, 256)), dim3(256), 0, stream>>>(a1h, a1l, a2h, a2l, c1, c2, E);

    // ---- precompute GEMMs ----
    // f_att = feats @ Wp^T + bp    (18432 x 512, K=2048, nkt=64 even)
    gemm_sp<128, 128, 32, true><<<dim3(4, 144), 256, 0, stream>>>(
        feats, nullptr, nullptr, Dd, wph, wpl, 2048, f_att, 512, 512, 2048, bp, nullptr, nullptr);
    fmean_kernel<<<dim3(Bsz), dim3(256), 0, stream>>>(f_att, f_mean, fmh, fml);
    // g1c = f_mean @ Wih1[:,Em:]^T + bih1 + bhh1   (512 x 2048, K=512)
    gemm_sp<64, 64, 64, false><<<dim3(32, 8), 256, 0, stream>>>(
        nullptr, fmh, fml, 512, w1ch, w1cl, 512, g1c, 2048, 2048, 512, bih1, bhh1, nullptr);
    // att_f = f_att @ Wa1[:,H:]^T + ba1   (18432 x 512, K=512, nkt=16 even)
    gemm_sp<128, 128, 32, true><<<dim3(4, 144), 256, 0, stream>>>(
        f_att, nullptr, nullptr, 512, wafh, wafl, 512, att_f, 512, 512, 512, ba1, nullptr, nullptr);

    // ---- decode loop ----
    for (int t = 0; t < TSTEPS; ++t) {
        // g1 = A1 @ W1p^T + g1c   (512 x 2048, K=832)
        gemm_sp<64, 64, 64, false><<<dim3(32, 8), 256, 0, stream>>>(
            nullptr, a1h, a1l, K1, w1ph, w1pl, K1, gbuf, 2048, 2048, K1, nullptr, nullptr, g1c);
        // h1 -> A2 cols [0,512) AND A1 cols [300,812)
        lstm_cell_kernel<<<dim3(Bsz * Hh / 256), dim3(256), 0, stream>>>(
            gbuf, c1, a2h, a2l, K2, 0, a1h, a1l, K1, Em);
        // q = h1 @ Wa1[:,:H]^T   (512 x 512, K=512)
        gemm_sp<64, 64, 64, false><<<dim3(8, 8), 256, 0, stream>>>(
            nullptr, a2h, a2l, K2, wahh, wahl, 512, qbuf, 512, 512, 512, nullptr, nullptr, nullptr);
        attn_fused<<<dim3(Bsz), dim3(256), 0, stream>>>(att_f, qbuf, wa2, ba2, f_att, a2h, a2l);
        // g2 = A2 @ W2p^T + bih2 + bhh2   (512 x 2048, K=1536)
        gemm_sp<64, 64, 64, false><<<dim3(32, 8), 256, 0, stream>>>(
            nullptr, a2h, a2l, K2, w2ph, w2pl, K2, gbuf, 2048, 2048, K2, bih2, bhh2, nullptr);
        lstm_cell_kernel<<<dim3(Bsz * Hh / 256), dim3(256), 0, stream>>>(
            gbuf, c2, a2h, a2l, K2, 1024, nullptr, nullptr, 0, 0);
        // logits = h2 @ Wo^T + bo   (512 x 10000, K=512)
        gemm_sp<64, 64, 64, false><<<dim3(158, 8), 256, 0, stream>>>(
            nullptr, a2h + 1024, a2l + 1024, K2, woh, wol, 512, logits, Vv, Vv, 512, bo, nullptr, nullptr);
        argmax_embed_kernel<<<dim3(Bsz), dim3(256), 0, stream>>>(logits, E, a1h, a1l, out, t);
    }
}